// Round 14
// baseline (251.515 us; speedup 1.0000x reference)
//
#include <hip/hip_runtime.h>
#include <cstdint>

typedef _Float16 f16;
typedef f16 f16x2 __attribute__((ext_vector_type(2)));
typedef f16 f16x4 __attribute__((ext_vector_type(4)));
typedef f16 f16x8 __attribute__((ext_vector_type(8)));
typedef float f32x4 __attribute__((ext_vector_type(4)));
typedef float f32x16 __attribute__((ext_vector_type(16)));

#define MFMA16F(a, b, c) __builtin_amdgcn_mfma_f32_16x16x32_f16(a, b, c, 0, 0, 0)
#define MFMA32F(a, b, c) __builtin_amdgcn_mfma_f32_32x32x16_f16(a, b, c, 0, 0, 0)

static constexpr int N = 4096;    // 64*64 tokens
static constexpr int CDIM = 128;  // channels
static constexpr int NH = 4;      // heads
static constexpr int DH = 32;     // dim per head
static constexpr uint32_t NBLK = 512;

__device__ __forceinline__ f16x2 cvt_pk(float a, float b) {
    return __builtin_bit_cast(f16x2, __builtin_amdgcn_cvt_pkrtz(a, b));
}

// 8 f32 -> f16x8 with scale
__device__ __forceinline__ f16x8 cvt8(const float* p, float sc) {
    struct Q4 { f16x2 a, b, c, d; } q{cvt_pk(p[0] * sc, p[1] * sc), cvt_pk(p[2] * sc, p[3] * sc),
                                      cvt_pk(p[4] * sc, p[5] * sc), cvt_pk(p[6] * sc, p[7] * sc)};
    return __builtin_bit_cast(f16x8, q);
}

// software grid barrier: all NBLK blocks co-resident by construction
// (LDS 43008 B -> 3 blocks/CU capacity = 768 >= 512). __threadfence() on
// gfx950 emits buffer_wbl2/buffer_inv -> cross-XCD L2 visibility.
__device__ __forceinline__ void grid_barrier(uint32_t* cnt) {
    __syncthreads();  // compiler emits vmcnt(0) drain before s_barrier
    if (threadIdx.x == 0) {
        __threadfence();  // release: write-back dirty L2 to L3
        __hip_atomic_fetch_add(cnt, 1u, __ATOMIC_RELAXED, __HIP_MEMORY_SCOPE_AGENT);
        while (__hip_atomic_load(cnt, __ATOMIC_RELAXED, __HIP_MEMORY_SCOPE_AGENT) < NBLK)
            __builtin_amdgcn_s_sleep(2);
        __threadfence();  // acquire: invalidate this XCD's L2/L1
    }
    __syncthreads();
}

// ---------------- mega kernel: proj_qkv | barrier | flash | barrier | proj_o ----
__global__ __launch_bounds__(512, 4) void mega(const float* __restrict__ x,
                                               const float* __restrict__ wq,
                                               const float* __restrict__ wk,
                                               const float* __restrict__ wv,
                                               const float* __restrict__ wo,
                                               const float* __restrict__ bo,
                                               f16* __restrict__ Q,
                                               f16* __restrict__ K,
                                               f16* __restrict__ V,
                                               f16* __restrict__ A,
                                               float* __restrict__ out,
                                               uint32_t* __restrict__ bar) {
    __shared__ __align__(16) char smem[43008];
    const int tid = threadIdx.x;
    const int blk = blockIdx.x;
    const int sub = tid >> 8, t8 = tid & 255;
    const int lane8 = t8 & 63, w8 = t8 >> 6;
    const int cr = lane8 & 15, quad = lane8 >> 4;

    // ================= Phase A: QKV projection =================
    {
        const int s = blk * 2 + sub;  // 0..1023; tasks: wt(3) x b(4) x tile64(64) = 768
        const bool active = s < 768;
        f16* xT = (f16*)(smem + sub * 17408);  // [64][136]
        f16x8 wfr[2][4];
        int b = 0, wt = 0, tile = 0;
        if (active) {
            wt = s >> 8;
            b = (s >> 6) & 3;
            tile = s & 63;
            const int n0 = tile * 64;
            const float* Wsrc = (wt == 0) ? wq : ((wt == 1) ? wk : wv);
            const float wsc = (wt == 0) ? (0.17677669529663687f * 1.4426950408889634f) : 1.0f;
#pragma unroll
            for (int ot2 = 0; ot2 < 2; ++ot2) {
                int ot = w8 * 2 + ot2;
#pragma unroll
                for (int ks = 0; ks < 4; ++ks)
                    wfr[ot2][ks] = cvt8(&Wsrc[(ot * 16 + cr) * 128 + ks * 32 + quad * 8], wsc);
            }
            const float* xb = x + (size_t)b * CDIM * N;
            for (int i = t8; i < 2048; i += 256) {  // 8 float4/thread
                int n4 = (i & 15) * 4, cc = i >> 4;
                const float4 v = *(const float4*)&xb[(size_t)cc * N + n0 + n4];
                xT[(n4 + 0) * 136 + cc] = (f16)v.x;
                xT[(n4 + 1) * 136 + cc] = (f16)v.y;
                xT[(n4 + 2) * 136 + cc] = (f16)v.z;
                xT[(n4 + 3) * 136 + cc] = (f16)v.w;
            }
        }
        __syncthreads();
        if (active) {
            const int n0 = tile * 64;
            const int sg = ((quad & 1) << 1) | (quad >> 1);
            for (int nt = 0; nt < 4; ++nt) {
                f16x8 bfr[4];
#pragma unroll
                for (int ks = 0; ks < 4; ++ks)
                    bfr[ks] = *(const f16x8*)&xT[(nt * 16 + cr) * 136 + ks * 32 + quad * 8];
#pragma unroll
                for (int ot2 = 0; ot2 < 2; ++ot2) {
                    int ot = w8 * 2 + ot2;
                    f32x4 acc = {0.f, 0.f, 0.f, 0.f};
                    if (wt < 2) {
                        // D[o][n] -> d-contiguous f16x4 store
#pragma unroll
                        for (int ks = 0; ks < 4; ++ks)
                            acc = MFMA16F(wfr[ot2][ks], bfr[ks], acc);
                        f16* dst = (wt == 0) ? Q : K;
                        int n = n0 + nt * 16 + cr;
                        int o0 = ot * 16 + quad * 4, hh = o0 >> 5, d0 = o0 & 31;
                        f16x4 v4 = {(f16)acc[0], (f16)acc[1], (f16)acc[2], (f16)acc[3]};
                        *(f16x4*)(dst + (((size_t)(b * NH + hh) * N + n) * DH + d0)) = v4;
                    } else {
                        // swapped: D[key][o] -> 4 consecutive kperm slots
#pragma unroll
                        for (int ks = 0; ks < 4; ++ks)
                            acc = MFMA16F(bfr[ks], wfr[ot2][ks], acc);
                        int o = ot * 16 + cr, hh = o >> 5, d = o & 31;
                        f16x4 v4 = {(f16)acc[0], (f16)acc[1], (f16)acc[2], (f16)acc[3]};
                        *(f16x4*)(V + ((size_t)(b * NH + hh) * 64 + tile) * 2048 +
                                  d * 64 + nt * 16 + sg * 4) = v4;
                    }
                }
            }
        }
    }

    grid_barrier(&bar[0]);

    // ================= Phase B: flash attention (R12 body, frozen) =================
    {
        const int gid = blk;
        const int bh = gid & 15;
        const int qblk = gid >> 4;  // 0..31
        const int w = tid >> 6, lane = tid & 63;
        const int l31 = lane & 31, h = lane >> 5;
        const int qg = w & 1, kh = w >> 1;
        const int qbase = qblk * 128 + qg * 64;

        f16* Kl = (f16*)smem;                     // 4 quarters x 2560 f16
        f16* Vlb = (f16*)(smem + 20480);          // 4 quarters x 2304 f16
        float* lred = (float*)(smem + 38912);     // [8][64]
        float* lred1 = (float*)(smem + 40960);    // [8][64]

        const f16* Qb = Q + (size_t)bh * N * DH;
        const f16* Kb = K + (size_t)bh * N * DH;
        const f16* Vt = V + (size_t)bh * 64 * 2048;

        const int qtr = tid >> 7, t = tid & 127;
        const f16* ksrc = Kb + (size_t)(qtr * 16) * 2048 + t * 16;
        const f16* vsrc = Vt + (size_t)(qtr * 16) * 2048 + t * 16;
        f16* kdst = Kl + qtr * 2560 + (t >> 1) * 40 + (t & 1) * 16;
        f16* vdst = Vlb + qtr * 2304 + (t >> 2) * 72 + (t & 3) * 16;

        f16x8 qf[2][2];
#pragma unroll
        for (int qs = 0; qs < 2; ++qs)
#pragma unroll
            for (int dh = 0; dh < 2; ++dh)
                qf[qs][dh] = *(const f16x8*)&Qb[(qbase + qs * 32 + l31) * DH + dh * 16 + h * 8];

        const f16x2 C3 = {(f16)0.05550411f, (f16)0.05550411f};
        const f16x2 C2 = {(f16)0.24022651f, (f16)0.24022651f};
        const f16x2 C1 = {(f16)0.69314718f, (f16)0.69314718f};
        const f16x2 ONE2 = {(f16)1.0f, (f16)1.0f};

        f32x16 o2[2] = {};
        float lsum[2] = {0.f, 0.f};

        f16x8 kr0 = *(const f16x8*)(ksrc);
        f16x8 kr1 = *(const f16x8*)(ksrc + 8);
        f16x8 vr0 = *(const f16x8*)(vsrc);
        f16x8 vr1 = *(const f16x8*)(vsrc + 8);

        for (int kt = 0; kt < 16; ++kt) {
            __syncthreads();
            *(f16x8*)(kdst)     = kr0;
            *(f16x8*)(kdst + 8) = kr1;
            *(f16x8*)(vdst)     = vr0;
            *(f16x8*)(vdst + 8) = vr1;
            __syncthreads();
            if (kt < 15) {
                const size_t off = (size_t)(kt + 1) * 2048;
                kr0 = *(const f16x8*)(ksrc + off);
                kr1 = *(const f16x8*)(ksrc + off + 8);
                vr0 = *(const f16x8*)(vsrc + off);
                vr1 = *(const f16x8*)(vsrc + off + 8);
            }
            const f16* Kc = Kl + kh * 2560;
            const f16* Vc = Vlb + kh * 2304;

#pragma unroll
            for (int g2 = 0; g2 < 2; ++g2) {
                f16x8 kf0 = *(const f16x8*)&Kc[(g2 * 32 + l31) * 40 + h * 8];
                f16x8 kf1 = *(const f16x8*)&Kc[(g2 * 32 + l31) * 40 + 16 + h * 8];
                f16x8 av0 = *(const f16x8*)&Vc[l31 * 72 + g2 * 32 + h * 8];
                f16x8 av1 = *(const f16x8*)&Vc[l31 * 72 + g2 * 32 + 16 + h * 8];
#pragma unroll
                for (int qs = 0; qs < 2; ++qs) {
                    f32x16 sc = {};
                    sc = MFMA32F(kf0, qf[qs][0], sc);
                    sc = MFMA32F(kf1, qf[qs][1], sc);

                    f16x2 p[8];
#pragma unroll
                    for (int i = 0; i < 8; ++i) {
                        f16x2 xx = cvt_pk(sc[2 * i], sc[2 * i + 1]);
                        f16x2 tt = xx * C3 + C2;
                        tt = xx * tt + C1;
                        p[i] = xx * tt + ONE2;
                    }
                    struct P4 { f16x2 a, b, c, d; };
                    P4 t0{p[0], p[1], p[2], p[3]};
                    P4 t1{p[4], p[5], p[6], p[7]};
                    f16x8 pB0 = __builtin_bit_cast(f16x8, t0);
                    f16x8 pB1 = __builtin_bit_cast(f16x8, t1);

                    o2[qs] = MFMA32F(av0, pB0, o2[qs]);
                    o2[qs] = MFMA32F(av1, pB1, o2[qs]);

                    f16x2 s01 = p[0] + p[1], s23 = p[2] + p[3];
                    f16x2 s45 = p[4] + p[5], s67 = p[6] + p[7];
                    f16x2 sa = s01 + s23, sb = s45 + s67;
                    f16x2 s = sa + sb;
                    lsum[qs] += (float)s[0] + (float)s[1];
                }
            }
        }

        lred[w * 64 + lane] = lsum[0];
        lred1[w * 64 + lane] = lsum[1];

        float* red = (float*)smem;  // overlay (reduction records, 30720 B)
        const int b = bh >> 2, hh = bh & 3;
#pragma unroll
        for (int qs = 0; qs < 2; ++qs) {
            __syncthreads();
            if (kh > 0) {
                float* r = red + (((kh - 1) * 2 + qg) * 64 + lane) * 20;
                *(f32x4*)(r + 0)  = (f32x4){o2[qs][0], o2[qs][1], o2[qs][2], o2[qs][3]};
                *(f32x4*)(r + 4)  = (f32x4){o2[qs][4], o2[qs][5], o2[qs][6], o2[qs][7]};
                *(f32x4*)(r + 8)  = (f32x4){o2[qs][8], o2[qs][9], o2[qs][10], o2[qs][11]};
                *(f32x4*)(r + 12) = (f32x4){o2[qs][12], o2[qs][13], o2[qs][14], o2[qs][15]};
            }
            __syncthreads();
            if (kh == 0) {
                f32x16 o = o2[qs];
#pragma unroll
                for (int j = 0; j < 3; ++j) {
                    const float* r = red + ((j * 2 + qg) * 64 + lane) * 20;
#pragma unroll
                    for (int i = 0; i < 16; ++i) o[i] += r[i];
                }
                float l = 0.f;
                const float* lr = qs ? lred1 : lred;
#pragma unroll
                for (int j = 0; j < 4; ++j)
                    l += lr[(j * 2 + qg) * 64 + l31] + lr[(j * 2 + qg) * 64 + 32 + l31];
                float inv = __builtin_amdgcn_rcpf(l);
                f16* Ob = A + ((size_t)b * N + qbase + qs * 32 + l31) * CDIM + hh * DH;
#pragma unroll
                for (int rg = 0; rg < 4; ++rg) {
                    const int d0 = rg * 8 + h * 4;
                    f16x4 v = {(f16)(o[rg * 4 + 0] * inv), (f16)(o[rg * 4 + 1] * inv),
                               (f16)(o[rg * 4 + 2] * inv), (f16)(o[rg * 4 + 3] * inv)};
                    *(f16x4*)(Ob + d0) = v;
                }
            }
        }
    }

    grid_barrier(&bar[16]);

    // ================= Phase C: output projection =================
    {
        const int s = blk * 2 + sub;  // 0..1023: zs(2) x b(4) x ntile32(128)
        const int zs = s >> 9, b = (s >> 7) & 3, ntile = s & 127;
        const int n0 = ntile * 32;
        f16* aT = (f16*)(smem + sub * 8704);  // [32][136]
        const f16* Ab = A + (size_t)b * N * CDIM;
        const int ot = zs * 4 + w8;
        const int o = ot * 16 + cr;

        f16x8 wfr[4];
#pragma unroll
        for (int ks = 0; ks < 4; ++ks)
            wfr[ks] = cvt8(&wo[(ot * 16 + cr) * 128 + ks * 32 + quad * 8], 1.0f);
        const float bov = bo[o];
        float* orow = out + (size_t)(b * CDIM + o) * N + n0;

        for (int i = t8; i < 512; i += 256) {  // 2 b128/thread
            int c8 = (i & 15) * 8, n = i >> 4;
            *(f16x8*)&aT[n * 136 + c8] = *(const f16x8*)&Ab[(size_t)(n0 + n) * CDIM + c8];
        }
        __syncthreads();

        for (int nt = 0; nt < 2; ++nt) {
            f16x8 bfr[4];
#pragma unroll
            for (int ks = 0; ks < 4; ++ks)
                bfr[ks] = *(const f16x8*)&aT[(nt * 16 + cr) * 136 + ks * 32 + quad * 8];
            f32x4 acc = {0.f, 0.f, 0.f, 0.f};
#pragma unroll
            for (int ks = 0; ks < 4; ++ks)
                acc = MFMA16F(bfr[ks], wfr[ks], acc);  // D[n][o]
            f32x4 res = {acc[0] + bov, acc[1] + bov, acc[2] + bov, acc[3] + bov};
            *(f32x4*)(orow + nt * 16 + quad * 4) = res;
        }
    }
}

// ---------------- launch ----------------
extern "C" void kernel_launch(void* const* d_in, const int* in_sizes, int n_in,
                              void* d_out, int out_size, void* d_ws, size_t ws_size,
                              hipStream_t stream) {
    const float* x  = (const float*)d_in[0];
    const float* wq = (const float*)d_in[1];
    const float* wk = (const float*)d_in[2];
    const float* wv = (const float*)d_in[3];
    const float* wo = (const float*)d_in[4];
    const float* bo = (const float*)d_in[5];

    char* ws = (char*)d_ws;
    f16* Q = (f16*)(ws);                       // 4 MB  [bh][n][32]
    f16* K = (f16*)(ws + ((size_t)4 << 20));   // 4 MB  [bh][n][32]
    f16* V = (f16*)(ws + ((size_t)8 << 20));   // 4 MB  [bh][tile][d32][kperm64]
    f16* A = (f16*)(ws + ((size_t)12 << 20));  // 4 MB  [b][n][128]
    uint32_t* bar = (uint32_t*)(ws + ((size_t)16 << 20));  // 2 counters

    hipMemsetAsync(bar, 0, 128, stream);
    mega<<<NBLK, 512, 0, stream>>>(x, wq, wk, wv, wo, bo, Q, K, V, A, (float*)d_out, bar);
}

// Round 15
// 167.370 us; speedup vs baseline: 1.5027x; 1.5027x over previous
//
#include <hip/hip_runtime.h>
#include <cstdint>

typedef _Float16 f16;
typedef f16 f16x2 __attribute__((ext_vector_type(2)));
typedef f16 f16x4 __attribute__((ext_vector_type(4)));
typedef f16 f16x8 __attribute__((ext_vector_type(8)));
typedef float f32x4 __attribute__((ext_vector_type(4)));
typedef float f32x16 __attribute__((ext_vector_type(16)));

#define MFMA16F(a, b, c) __builtin_amdgcn_mfma_f32_16x16x32_f16(a, b, c, 0, 0, 0)
#define MFMA32F(a, b, c) __builtin_amdgcn_mfma_f32_32x32x16_f16(a, b, c, 0, 0, 0)

static constexpr int N = 4096;    // 64*64 tokens
static constexpr int CDIM = 128;  // channels
static constexpr int NH = 4;      // heads
static constexpr int DH = 32;     // dim per head
static constexpr uint32_t NBLK = 512;

__device__ __forceinline__ f16x2 cvt_pk(float a, float b) {
    return __builtin_bit_cast(f16x2, __builtin_amdgcn_cvt_pkrtz(a, b));
}

// 8 f32 -> f16x8 with scale
__device__ __forceinline__ f16x8 cvt8(const float* p, float sc) {
    struct Q4 { f16x2 a, b, c, d; } q{cvt_pk(p[0] * sc, p[1] * sc), cvt_pk(p[2] * sc, p[3] * sc),
                                      cvt_pk(p[4] * sc, p[5] * sc), cvt_pk(p[6] * sc, p[7] * sc)};
    return __builtin_bit_cast(f16x8, q);
}

// -------- designated-writer grid barrier (no full-cache fences) --------
// layout (u32 idx in base): [0]=cntA arrivals, [32]=cntB wbl2-done,
// [64]=cntW winners, [96+xcc]=per-XCD first-arriver flag.
// All counters are far-atomics (L3-coherent by themselves, relaxed).
// Correctness: __syncthreads drains vmcnt(0) -> this block's stores are in
// its XCD L2; one winner per XCD issues buffer_wbl2 AFTER all 512 blocks
// arrived -> all dirty inter-phase data reaches L3. No stale copies exist
// anywhere (first touch in this launch is the write; launch boundary
// invalidated caches), so no buffer_inv needed.
__device__ __forceinline__ void grid_barrier(uint32_t* base) {
    __syncthreads();  // emits s_waitcnt vmcnt(0) ... before s_barrier
    if (threadIdx.x == 0) {
        uint32_t xcc;
        asm volatile("s_getreg_b32 %0, hwreg(HW_REG_XCC_ID)" : "=s"(xcc));
        bool win = __hip_atomic_fetch_add(&base[96 + xcc], 1u, __ATOMIC_RELAXED,
                                          __HIP_MEMORY_SCOPE_AGENT) == 0u;
        if (win)
            __hip_atomic_fetch_add(&base[64], 1u, __ATOMIC_RELAXED,
                                   __HIP_MEMORY_SCOPE_AGENT);
        asm volatile("s_waitcnt vmcnt(0)" ::: "memory");  // cntW visible before cntA
        __hip_atomic_fetch_add(&base[0], 1u, __ATOMIC_RELAXED,
                               __HIP_MEMORY_SCOPE_AGENT);
        while (__hip_atomic_load(&base[0], __ATOMIC_RELAXED,
                                 __HIP_MEMORY_SCOPE_AGENT) < NBLK)
            __builtin_amdgcn_s_sleep(8);
        uint32_t nw = __hip_atomic_load(&base[64], __ATOMIC_RELAXED,
                                        __HIP_MEMORY_SCOPE_AGENT);
        if (win) {
            asm volatile("buffer_wbl2\n\ts_waitcnt vmcnt(0)" ::: "memory");
            __hip_atomic_fetch_add(&base[32], 1u, __ATOMIC_RELAXED,
                                   __HIP_MEMORY_SCOPE_AGENT);
        }
        while (__hip_atomic_load(&base[32], __ATOMIC_RELAXED,
                                 __HIP_MEMORY_SCOPE_AGENT) < nw)
            __builtin_amdgcn_s_sleep(8);
    }
    __syncthreads();
}

// ---------------- mega kernel: proj_qkv | barrier | flash | barrier | proj_o ----
__global__ __launch_bounds__(512, 4) void mega(const float* __restrict__ x,
                                               const float* __restrict__ wq,
                                               const float* __restrict__ wk,
                                               const float* __restrict__ wv,
                                               const float* __restrict__ wo,
                                               const float* __restrict__ bo,
                                               f16* __restrict__ Q,
                                               f16* __restrict__ K,
                                               f16* __restrict__ V,
                                               f16* __restrict__ A,
                                               float* __restrict__ out,
                                               uint32_t* __restrict__ bar) {
    __shared__ __align__(16) char smem[43008];
    const int tid = threadIdx.x;
    const int blk = blockIdx.x;
    const int sub = tid >> 8, t8 = tid & 255;
    const int lane8 = t8 & 63, w8 = t8 >> 6;
    const int cr = lane8 & 15, quad = lane8 >> 4;

    // ================= Phase A: QKV projection =================
    {
        const int s = blk * 2 + sub;  // 0..1023; tasks: wt(3) x b(4) x tile64(64) = 768
        const bool active = s < 768;
        f16* xT = (f16*)(smem + sub * 17408);  // [64][136]
        f16x8 wfr[2][4];
        int b = 0, wt = 0, tile = 0;
        if (active) {
            wt = s >> 8;
            b = (s >> 6) & 3;
            tile = s & 63;
            const int n0 = tile * 64;
            const float* Wsrc = (wt == 0) ? wq : ((wt == 1) ? wk : wv);
            const float wsc = (wt == 0) ? (0.17677669529663687f * 1.4426950408889634f) : 1.0f;
#pragma unroll
            for (int ot2 = 0; ot2 < 2; ++ot2) {
                int ot = w8 * 2 + ot2;
#pragma unroll
                for (int ks = 0; ks < 4; ++ks)
                    wfr[ot2][ks] = cvt8(&Wsrc[(ot * 16 + cr) * 128 + ks * 32 + quad * 8], wsc);
            }
            const float* xb = x + (size_t)b * CDIM * N;
            for (int i = t8; i < 2048; i += 256) {  // 8 float4/thread
                int n4 = (i & 15) * 4, cc = i >> 4;
                const float4 v = *(const float4*)&xb[(size_t)cc * N + n0 + n4];
                xT[(n4 + 0) * 136 + cc] = (f16)v.x;
                xT[(n4 + 1) * 136 + cc] = (f16)v.y;
                xT[(n4 + 2) * 136 + cc] = (f16)v.z;
                xT[(n4 + 3) * 136 + cc] = (f16)v.w;
            }
        }
        __syncthreads();
        if (active) {
            const int n0 = tile * 64;
            const int sg = ((quad & 1) << 1) | (quad >> 1);
            for (int nt = 0; nt < 4; ++nt) {
                f16x8 bfr[4];
#pragma unroll
                for (int ks = 0; ks < 4; ++ks)
                    bfr[ks] = *(const f16x8*)&xT[(nt * 16 + cr) * 136 + ks * 32 + quad * 8];
#pragma unroll
                for (int ot2 = 0; ot2 < 2; ++ot2) {
                    int ot = w8 * 2 + ot2;
                    f32x4 acc = {0.f, 0.f, 0.f, 0.f};
                    if (wt < 2) {
                        // D[o][n] -> d-contiguous f16x4 store
#pragma unroll
                        for (int ks = 0; ks < 4; ++ks)
                            acc = MFMA16F(wfr[ot2][ks], bfr[ks], acc);
                        f16* dst = (wt == 0) ? Q : K;
                        int n = n0 + nt * 16 + cr;
                        int o0 = ot * 16 + quad * 4, hh = o0 >> 5, d0 = o0 & 31;
                        f16x4 v4 = {(f16)acc[0], (f16)acc[1], (f16)acc[2], (f16)acc[3]};
                        *(f16x4*)(dst + (((size_t)(b * NH + hh) * N + n) * DH + d0)) = v4;
                    } else {
                        // swapped: D[key][o] -> 4 consecutive kperm slots
#pragma unroll
                        for (int ks = 0; ks < 4; ++ks)
                            acc = MFMA16F(bfr[ks], wfr[ot2][ks], acc);
                        int o = ot * 16 + cr, hh = o >> 5, d = o & 31;
                        f16x4 v4 = {(f16)acc[0], (f16)acc[1], (f16)acc[2], (f16)acc[3]};
                        *(f16x4*)(V + ((size_t)(b * NH + hh) * 64 + tile) * 2048 +
                                  d * 64 + nt * 16 + sg * 4) = v4;
                    }
                }
            }
        }
    }

    grid_barrier(&bar[0]);

    // ================= Phase B: flash attention (frozen body) =================
    {
        const int gid = blk;
        const int bh = gid & 15;
        const int qblk = gid >> 4;  // 0..31
        const int w = tid >> 6, lane = tid & 63;
        const int l31 = lane & 31, h = lane >> 5;
        const int qg = w & 1, kh = w >> 1;
        const int qbase = qblk * 128 + qg * 64;

        f16* Kl = (f16*)smem;                     // 4 quarters x 2560 f16
        f16* Vlb = (f16*)(smem + 20480);          // 4 quarters x 2304 f16
        float* lred = (float*)(smem + 38912);     // [8][64]
        float* lred1 = (float*)(smem + 40960);    // [8][64]

        const f16* Qb = Q + (size_t)bh * N * DH;
        const f16* Kb = K + (size_t)bh * N * DH;
        const f16* Vt = V + (size_t)bh * 64 * 2048;

        const int qtr = tid >> 7, t = tid & 127;
        const f16* ksrc = Kb + (size_t)(qtr * 16) * 2048 + t * 16;
        const f16* vsrc = Vt + (size_t)(qtr * 16) * 2048 + t * 16;
        f16* kdst = Kl + qtr * 2560 + (t >> 1) * 40 + (t & 1) * 16;
        f16* vdst = Vlb + qtr * 2304 + (t >> 2) * 72 + (t & 3) * 16;

        f16x8 qf[2][2];
#pragma unroll
        for (int qs = 0; qs < 2; ++qs)
#pragma unroll
            for (int dh = 0; dh < 2; ++dh)
                qf[qs][dh] = *(const f16x8*)&Qb[(qbase + qs * 32 + l31) * DH + dh * 16 + h * 8];

        const f16x2 C3 = {(f16)0.05550411f, (f16)0.05550411f};
        const f16x2 C2 = {(f16)0.24022651f, (f16)0.24022651f};
        const f16x2 C1 = {(f16)0.69314718f, (f16)0.69314718f};
        const f16x2 ONE2 = {(f16)1.0f, (f16)1.0f};

        f32x16 o2[2] = {};
        float lsum[2] = {0.f, 0.f};

        f16x8 kr0 = *(const f16x8*)(ksrc);
        f16x8 kr1 = *(const f16x8*)(ksrc + 8);
        f16x8 vr0 = *(const f16x8*)(vsrc);
        f16x8 vr1 = *(const f16x8*)(vsrc + 8);

        for (int kt = 0; kt < 16; ++kt) {
            __syncthreads();
            *(f16x8*)(kdst)     = kr0;
            *(f16x8*)(kdst + 8) = kr1;
            *(f16x8*)(vdst)     = vr0;
            *(f16x8*)(vdst + 8) = vr1;
            __syncthreads();
            if (kt < 15) {
                const size_t off = (size_t)(kt + 1) * 2048;
                kr0 = *(const f16x8*)(ksrc + off);
                kr1 = *(const f16x8*)(ksrc + off + 8);
                vr0 = *(const f16x8*)(vsrc + off);
                vr1 = *(const f16x8*)(vsrc + off + 8);
            }
            const f16* Kc = Kl + kh * 2560;
            const f16* Vc = Vlb + kh * 2304;

#pragma unroll
            for (int g2 = 0; g2 < 2; ++g2) {
                f16x8 kf0 = *(const f16x8*)&Kc[(g2 * 32 + l31) * 40 + h * 8];
                f16x8 kf1 = *(const f16x8*)&Kc[(g2 * 32 + l31) * 40 + 16 + h * 8];
                f16x8 av0 = *(const f16x8*)&Vc[l31 * 72 + g2 * 32 + h * 8];
                f16x8 av1 = *(const f16x8*)&Vc[l31 * 72 + g2 * 32 + 16 + h * 8];
#pragma unroll
                for (int qs = 0; qs < 2; ++qs) {
                    f32x16 sc = {};
                    sc = MFMA32F(kf0, qf[qs][0], sc);
                    sc = MFMA32F(kf1, qf[qs][1], sc);

                    f16x2 p[8];
#pragma unroll
                    for (int i = 0; i < 8; ++i) {
                        f16x2 xx = cvt_pk(sc[2 * i], sc[2 * i + 1]);
                        f16x2 tt = xx * C3 + C2;
                        tt = xx * tt + C1;
                        p[i] = xx * tt + ONE2;
                    }
                    struct P4 { f16x2 a, b, c, d; };
                    P4 t0{p[0], p[1], p[2], p[3]};
                    P4 t1{p[4], p[5], p[6], p[7]};
                    f16x8 pB0 = __builtin_bit_cast(f16x8, t0);
                    f16x8 pB1 = __builtin_bit_cast(f16x8, t1);

                    o2[qs] = MFMA32F(av0, pB0, o2[qs]);
                    o2[qs] = MFMA32F(av1, pB1, o2[qs]);

                    f16x2 s01 = p[0] + p[1], s23 = p[2] + p[3];
                    f16x2 s45 = p[4] + p[5], s67 = p[6] + p[7];
                    f16x2 sa = s01 + s23, sb = s45 + s67;
                    f16x2 s = sa + sb;
                    lsum[qs] += (float)s[0] + (float)s[1];
                }
            }
        }

        lred[w * 64 + lane] = lsum[0];
        lred1[w * 64 + lane] = lsum[1];

        float* red = (float*)smem;  // overlay (reduction records, 30720 B)
        const int b = bh >> 2, hh = bh & 3;
#pragma unroll
        for (int qs = 0; qs < 2; ++qs) {
            __syncthreads();
            if (kh > 0) {
                float* r = red + (((kh - 1) * 2 + qg) * 64 + lane) * 20;
                *(f32x4*)(r + 0)  = (f32x4){o2[qs][0], o2[qs][1], o2[qs][2], o2[qs][3]};
                *(f32x4*)(r + 4)  = (f32x4){o2[qs][4], o2[qs][5], o2[qs][6], o2[qs][7]};
                *(f32x4*)(r + 8)  = (f32x4){o2[qs][8], o2[qs][9], o2[qs][10], o2[qs][11]};
                *(f32x4*)(r + 12) = (f32x4){o2[qs][12], o2[qs][13], o2[qs][14], o2[qs][15]};
            }
            __syncthreads();
            if (kh == 0) {
                f32x16 o = o2[qs];
#pragma unroll
                for (int j = 0; j < 3; ++j) {
                    const float* r = red + ((j * 2 + qg) * 64 + lane) * 20;
#pragma unroll
                    for (int i = 0; i < 16; ++i) o[i] += r[i];
                }
                float l = 0.f;
                const float* lr = qs ? lred1 : lred;
#pragma unroll
                for (int j = 0; j < 4; ++j)
                    l += lr[(j * 2 + qg) * 64 + l31] + lr[(j * 2 + qg) * 64 + 32 + l31];
                float inv = __builtin_amdgcn_rcpf(l);
                f16* Ob = A + ((size_t)b * N + qbase + qs * 32 + l31) * CDIM + hh * DH;
#pragma unroll
                for (int rg = 0; rg < 4; ++rg) {
                    const int d0 = rg * 8 + h * 4;
                    f16x4 v = {(f16)(o[rg * 4 + 0] * inv), (f16)(o[rg * 4 + 1] * inv),
                               (f16)(o[rg * 4 + 2] * inv), (f16)(o[rg * 4 + 3] * inv)};
                    *(f16x4*)(Ob + d0) = v;
                }
            }
        }
    }

    grid_barrier(&bar[256]);

    // ================= Phase C: output projection =================
    {
        const int s = blk * 2 + sub;  // 0..1023: zs(2) x b(4) x ntile32(128)
        const int zs = s >> 9, b = (s >> 7) & 3, ntile = s & 127;
        const int n0 = ntile * 32;
        f16* aT = (f16*)(smem + sub * 8704);  // [32][136]
        const f16* Ab = A + (size_t)b * N * CDIM;
        const int ot = zs * 4 + w8;
        const int o = ot * 16 + cr;

        f16x8 wfr[4];
#pragma unroll
        for (int ks = 0; ks < 4; ++ks)
            wfr[ks] = cvt8(&wo[(ot * 16 + cr) * 128 + ks * 32 + quad * 8], 1.0f);
        const float bov = bo[o];
        float* orow = out + (size_t)(b * CDIM + o) * N + n0;

        for (int i = t8; i < 512; i += 256) {  // 2 b128/thread
            int c8 = (i & 15) * 8, n = i >> 4;
            *(f16x8*)&aT[n * 136 + c8] = *(const f16x8*)&Ab[(size_t)(n0 + n) * CDIM + c8];
        }
        __syncthreads();

        for (int nt = 0; nt < 2; ++nt) {
            f16x8 bfr[4];
#pragma unroll
            for (int ks = 0; ks < 4; ++ks)
                bfr[ks] = *(const f16x8*)&aT[(nt * 16 + cr) * 136 + ks * 32 + quad * 8];
            f32x4 acc = {0.f, 0.f, 0.f, 0.f};
#pragma unroll
            for (int ks = 0; ks < 4; ++ks)
                acc = MFMA16F(bfr[ks], wfr[ks], acc);  // D[n][o]
            f32x4 res = {acc[0] + bov, acc[1] + bov, acc[2] + bov, acc[3] + bov};
            *(f32x4*)(orow + nt * 16 + quad * 4) = res;
        }
    }
}

// ---------------- launch ----------------
extern "C" void kernel_launch(void* const* d_in, const int* in_sizes, int n_in,
                              void* d_out, int out_size, void* d_ws, size_t ws_size,
                              hipStream_t stream) {
    const float* x  = (const float*)d_in[0];
    const float* wq = (const float*)d_in[1];
    const float* wk = (const float*)d_in[2];
    const float* wv = (const float*)d_in[3];
    const float* wo = (const float*)d_in[4];
    const float* bo = (const float*)d_in[5];

    char* ws = (char*)d_ws;
    f16* Q = (f16*)(ws);                       // 4 MB  [bh][n][32]
    f16* K = (f16*)(ws + ((size_t)4 << 20));   // 4 MB  [bh][n][32]
    f16* V = (f16*)(ws + ((size_t)8 << 20));   // 4 MB  [bh][tile][d32][kperm64]
    f16* A = (f16*)(ws + ((size_t)12 << 20));  // 4 MB  [b][n][128]
    uint32_t* bar = (uint32_t*)(ws + ((size_t)16 << 20));  // 2 x 1KB barrier state

    hipMemsetAsync(bar, 0, 2048, stream);
    mega<<<NBLK, 512, 0, stream>>>(x, wq, wk, wv, wo, bo, Q, K, V, A, (float*)d_out, bar);
}